// Round 8
// baseline (157.439 us; speedup 1.0000x reference)
//
#include <hip/hip_runtime.h>
#include <stdint.h>
#include <math.h>

#define T0 256            // k0 block size
#define T1 512            // k1 block size
#define TPB 1024          // k2 block size
#define NB 2048           // histogram bins
#define SPLIT 8           // row split for scan blocks
#define LCAND 1024        // per-chunk candidate cap
#define CAND2 2048        // candidate cap in K2
#define PS0 2048          // presample count per slot (k0)
#define L2E 1.44269504088896f

typedef float vfloat4 __attribute__((ext_vector_type(4)));
typedef unsigned long long ull;

// monotonic float -> uint key (ascending key == ascending float)
__device__ __forceinline__ unsigned fkey(float f) {
    unsigned u = __float_as_uint(f);
    return (u & 0x80000000u) ? ~u : (u | 0x80000000u);
}
__device__ __forceinline__ float funkey(unsigned k) {
    unsigned u = (k & 0x80000000u) ? (k ^ 0x80000000u) : ~k;
    return __uint_as_float(u);
}
__device__ __forceinline__ ull packkv(unsigned k, unsigned idx) {
    return ((ull)k << 32) | (ull)(~idx);    // ~idx: desc key sort => asc idx ties
}

// in-place suffix sum of h[0..NB) with 1024 threads (k2 only).
__device__ __forceinline__ void suffix_scan_2048(unsigned* h, unsigned* wscr, int tid)
{
    const int lane = tid & 63, w = tid >> 6;
    const int i0 = 2047 - 2 * tid;
    const int i1 = 2046 - 2 * tid;
    unsigned a = h[i0], b = h[i1];
    unsigned s = a + b;
    unsigned inc = s;
    #pragma unroll
    for (int d = 1; d < 64; d <<= 1) { unsigned o = __shfl_up(inc, d); if (lane >= d) inc += o; }
    if (lane == 63) wscr[w] = inc;
    __syncthreads();
    if (w == 0) {
        unsigned v = (lane < 16) ? wscr[lane] : 0u;
        unsigned vi = v;
        #pragma unroll
        for (int d = 1; d < 16; d <<= 1) { unsigned o = __shfl_up(vi, d); if (lane >= d) vi += o; }
        if (lane < 16) wscr[16 + lane] = vi - v;
    }
    __syncthreads();
    unsigned off = wscr[16 + w] + (inc - s);
    h[i0] = off + a;
    h[i1] = off + a + b;
    __syncthreads();
}

// ============================ K0 ============================
// grid = SPLIT*B, 256 thr. Presample (first PS0 elems of the chunk) ->
// per-slot quantile cut + presample max (softmax offset). Tiny: 8 KB/block.
__global__ __launch_bounds__(T0)
void k0_cut(const float* __restrict__ logits,
            const float* __restrict__ temps,
            const int* __restrict__ top_ks,
            float* __restrict__ ws_cy,     // [slot] y-space offset
            unsigned* __restrict__ ws_cut, // [slot]
            int V, int Vq)
{
    const int slot = blockIdx.x;
    const int b = slot / SPLIT, s = slot % SPLIT;
    const int tid = threadIdx.x, lane = tid & 63, w = tid >> 6;
    const int start = s * Vq;
    const int len = min(Vq, V - start);

    __shared__ unsigned hist[NB];
    __shared__ unsigned uscr[16];
    __shared__ float fred[8];
    __shared__ int bstar;

    if (len <= 0) {
        if (tid == 0) { ws_cut[slot] = 0xFFFFFFFFu; ws_cy[slot] = -1e30f; }
        return;
    }
    for (int i = tid; i < NB; i += T0) hist[i] = 0;
    if (tid == 0) bstar = 0;
    __syncthreads();

    const float* __restrict__ row = logits + (size_t)b * V + start;
    const vfloat4* __restrict__ row4 = (const vfloat4*)row;
    const int nps = min(len, PS0);
    const int np4 = nps >> 2;

    float m0 = -1e30f;
    for (int i = tid; i < np4; i += T0) {
        vfloat4 v = row4[i];
        #pragma unroll
        for (int j = 0; j < 4; ++j) {
            float lv = v[j];
            m0 = fmaxf(m0, lv);
            atomicAdd(&hist[fkey(lv) >> 21], 1u);
        }
    }
    for (int i = (np4 << 2) + tid; i < nps; i += T0) {
        float lv = row[i];
        m0 = fmaxf(m0, lv);
        atomicAdd(&hist[fkey(lv) >> 21], 1u);
    }
    #pragma unroll
    for (int d = 32; d > 0; d >>= 1) m0 = fmaxf(m0, __shfl_down(m0, d));
    if (lane == 0) fred[w] = m0;
    __syncthreads();
    if (tid == 0) {
        float mm = fred[0];
        for (int j = 1; j < T0 / 64; ++j) mm = fmaxf(mm, fred[j]);
        fred[4] = mm;
    }
    __syncthreads();
    const float m0max = fred[4];

    // suffix scan: thread t owns 8 reversed bins
    unsigned sloc[8];
    unsigned acc = 0;
    #pragma unroll
    for (int j = 0; j < 8; ++j) { acc += hist[2047 - (8 * tid + j)]; sloc[j] = acc; }
    __syncthreads();
    unsigned inc = acc;
    #pragma unroll
    for (int d = 1; d < 64; d <<= 1) { unsigned o = __shfl_up(inc, d); if (lane >= d) inc += o; }
    if (lane == 63) uscr[w] = inc;
    __syncthreads();
    if (tid == 0) {
        unsigned o = 0;
        for (int j = 0; j < T0 / 64; ++j) { unsigned t = uscr[j]; uscr[8 + j] = o; o += t; }
    }
    __syncthreads();
    unsigned off = uscr[8 + w] + (inc - acc);
    #pragma unroll
    for (int j = 0; j < 8; ++j) hist[2047 - (8 * tid + j)] = off + sloc[j];
    __syncthreads();

    int K = top_ks[b]; K = max(K, 1); K = min(K, 1024);
    float sexp = (float)K * (float)nps / (float)V;
    unsigned TGT = (unsigned)(sexp + 6.0f * sqrtf(sexp) + 16.5f);
    if (TGT > (unsigned)nps) TGT = (unsigned)nps;
    for (int e = tid; e < NB; e += T0) {
        unsigned Se = hist[e];
        unsigned Sn = (e < NB - 1) ? hist[e + 1] : 0u;
        if (Se >= TGT && Sn < TGT) bstar = e;   // unique writer
    }
    __syncthreads();
    if (tid == 0) {
        ws_cut[slot] = (unsigned)bstar << 21;
        ws_cy[slot]  = m0max / temps[b];        // Cy (y-space)
    }
}

// ============================ K1 ============================
// grid = SPLIT*B, 512 thr. PURE streaming: zero out_probs chunk + Z-sum +
// candidate gather (cut from k0). No histogram, no phase barrier.
__global__ __launch_bounds__(T1)
void k1_scan(const float* __restrict__ logits,
             const float* __restrict__ temps,
             float* __restrict__ out_probs,
             const float* __restrict__ ws_cy,
             const unsigned* __restrict__ ws_cut,
             float* __restrict__ ws_z,      // [slot]
             unsigned* __restrict__ ws_cnt, // [slot] raw (overflow visible)
             unsigned* __restrict__ ws_maxk,// [slot] max candidate key
             ull* __restrict__ ws_cand,     // [slot][LCAND]
             int V, int Vq)
{
    const int slot = blockIdx.x;
    const int b = slot / SPLIT, s = slot % SPLIT;
    const int tid = threadIdx.x, lane = tid & 63, w = tid >> 6;
    const int start = s * Vq;
    const int len = min(Vq, V - start);

    __shared__ float fred[16];
    __shared__ unsigned cnt;

    if (len <= 0) {
        if (tid == 0) { ws_z[slot] = 0.0f; ws_cnt[slot] = 0u; ws_maxk[slot] = 0u; }
        return;
    }
    if (tid == 0) cnt = 0;
    __syncthreads();

    const float invT = 1.0f / temps[b];
    const float Cy = ws_cy[slot];
    const unsigned cutkey = ws_cut[slot];
    const float cutval = funkey(cutkey);

    const float* __restrict__ row = logits + (size_t)b * V + start;
    const vfloat4* __restrict__ row4 = (const vfloat4*)row;
    const int L4 = len >> 2;

    // zero epilogue (plain stores; fill-kernel shows these hit ~6 TB/s)
    {
        float* __restrict__ orow = out_probs + (size_t)b * V + start;
        vfloat4* __restrict__ orow4 = (vfloat4*)orow;
        const vfloat4 z4 = (vfloat4)0.0f;
        for (int i = tid; i < L4; i += T1) orow4[i] = z4;
        for (int i = (L4 << 2) + tid; i < len; i += T1) orow[i] = 0.0f;
    }

    const float ca = invT * L2E;
    const float cb = -Cy * L2E;
    ull* gc = ws_cand + (size_t)slot * LCAND;

    float z0 = 0.0f, z1 = 0.0f, z2 = 0.0f, z3 = 0.0f, mb = -1e30f;

    #define E4(v) (exp2f(fmaf((v)[0], ca, cb)) + exp2f(fmaf((v)[1], ca, cb)) \
                 + exp2f(fmaf((v)[2], ca, cb)) + exp2f(fmaf((v)[3], ca, cb)))
    #define GATHER(v, ii) do {                                                  \
        bool c0 = (v)[0] >= cutval, c1 = (v)[1] >= cutval,                      \
             c2 = (v)[2] >= cutval, c3 = (v)[3] >= cutval;                      \
        if (c0 | c1 | c2 | c3) {                                                \
            mb = fmaxf(mb, fmaxf(fmaxf((v)[0], (v)[1]), fmaxf((v)[2], (v)[3])));\
            int nh = (int)c0 + (int)c1 + (int)c2 + (int)c3;                     \
            unsigned base = atomicAdd(&cnt, (unsigned)nh);                      \
            unsigned bi = (unsigned)(start + ((ii) << 2));                      \
            if (c0) { if (base < LCAND) gc[base] = packkv(fkey((v)[0]), bi+0); base++; } \
            if (c1) { if (base < LCAND) gc[base] = packkv(fkey((v)[1]), bi+1); base++; } \
            if (c2) { if (base < LCAND) gc[base] = packkv(fkey((v)[2]), bi+2); base++; } \
            if (c3) { if (base < LCAND) gc[base] = packkv(fkey((v)[3]), bi+3); base++; } \
        }                                                                       \
    } while (0)

    int i = tid;
    for (; i + 3 * T1 < L4; i += 4 * T1) {
        vfloat4 va = row4[i];
        vfloat4 vb = row4[i + T1];
        vfloat4 vc = row4[i + 2 * T1];
        vfloat4 vd = row4[i + 3 * T1];
        z0 += E4(va); z1 += E4(vb); z2 += E4(vc); z3 += E4(vd);
        GATHER(va, i); GATHER(vb, i + T1); GATHER(vc, i + 2 * T1); GATHER(vd, i + 3 * T1);
    }
    for (; i < L4; i += T1) {
        vfloat4 v = row4[i];
        z0 += E4(v);
        GATHER(v, i);
    }
    for (int j = (L4 << 2) + tid; j < len; j += T1) {
        float lv = row[j];
        z0 += exp2f(fmaf(lv, ca, cb));
        if (lv >= cutval) {
            mb = fmaxf(mb, lv);
            unsigned base = atomicAdd(&cnt, 1u);
            if (base < LCAND) gc[base] = packkv(fkey(lv), (unsigned)(start + j));
        }
    }
    #undef E4
    #undef GATHER

    float z = (z0 + z1) + (z2 + z3);
    __syncthreads();
    #pragma unroll
    for (int d = 32; d > 0; d >>= 1) {
        z += __shfl_down(z, d);
        mb = fmaxf(mb, __shfl_down(mb, d));
    }
    if (lane == 0) { fred[w] = z; fred[8 + w] = mb; }
    __syncthreads();
    if (tid == 0) {
        float zz = 0.0f, mm = -1e30f;
        for (int j = 0; j < T1 / 64; ++j) { zz += fred[j]; mm = fmaxf(mm, fred[8 + j]); }
        ws_z[slot] = zz;
        ws_cnt[slot] = cnt;
        ws_maxk[slot] = (cnt > 0u) ? fkey(mm) : 0u;
    }
}

// ============================ K2 ============================
// grid = B. Adaptive histogram over candidate lists -> exact threshold +
// scatter-sort; guards + full-row fallback.
__global__ __launch_bounds__(TPB)
void k2_sample(const float* __restrict__ logits,
               const float* __restrict__ temps,
               const int* __restrict__ top_ks,
               const float* __restrict__ top_ps,
               const float* __restrict__ min_ps,
               const float* __restrict__ uvec,
               const float* __restrict__ ws_cy,
               const float* __restrict__ ws_z,
               const unsigned* __restrict__ ws_cut,
               const unsigned* __restrict__ ws_cnt,
               const unsigned* __restrict__ ws_maxk,
               const ull* __restrict__ ws_cand,
               float* __restrict__ out_tok,
               float* __restrict__ out_probs,
               int V)
{
    const int b = blockIdx.x;
    const int tid = threadIdx.x, lane = tid & 63, w = tid >> 6;
    const float invT = 1.0f / temps[b];
    int Korig = top_ks[b]; Korig = max(Korig, 1); Korig = min(Korig, 1024);
    const unsigned Ku = (unsigned)Korig;
    const float top_p = top_ps[b], min_p = min_ps[b], uval = uvec[b];

    __shared__ __align__(16) char smem[53504];
    ull*            cand  = (ull*)(smem);                       // [2048] (fb path)
    ull*            cand2 = (ull*)(smem + 16384);               // [2048] sorted dest
    unsigned*       hist  = (unsigned*)(smem + 32768);          // [2049]
    unsigned short* cnts  = (unsigned short*)(smem + 41216);    // [2048]
    float*          sh_p  = (float*)(smem + 45312);             // [1024]
    float*          sh_c  = (float*)(smem + 49408);             // [1024]
    __shared__ unsigned uscr[32];
    __shared__ float fws[32];
    __shared__ unsigned scnt;
    __shared__ int sh_i1, sh_i2;
    __shared__ unsigned sh_u1;

    // ---- combine per-slot meta ----
    float Cy[SPLIT], zq[SPLIT];
    unsigned cutq[SPLIT], cntq[SPLIT], mkq[SPLIT];
    #pragma unroll
    for (int q = 0; q < SPLIT; ++q) {
        int sl = b * SPLIT + q;
        Cy[q] = ws_cy[sl]; zq[q] = ws_z[sl];
        cutq[q] = ws_cut[sl]; cntq[q] = ws_cnt[sl]; mkq[q] = ws_maxk[sl];
    }
    float Y = -1e30f;
    #pragma unroll
    for (int q = 0; q < SPLIT; ++q) if (cntq[q] > 0u) Y = fmaxf(Y, Cy[q]);
    float Z = 0.0f;
    #pragma unroll
    for (int q = 0; q < SPLIT; ++q)
        if (cntq[q] > 0u && zq[q] > 0.0f) Z += zq[q] * exp2f((Cy[q] - Y) * L2E);

    bool fb = false;
    unsigned cutmax = 0, mincut = 0xFFFFFFFFu, maxkey = 0;
    #pragma unroll
    for (int q = 0; q < SPLIT; ++q) {
        if (cntq[q] > (unsigned)LCAND) fb = true;          // list truncated
        if (cntq[q] > 0u) {
            if (!isfinite(zq[q])) fb = true;               // Z overflow -> exact path
            cutmax = max(cutmax, cutq[q]);
            mincut = min(mincut, cutq[q]);
            maxkey = max(maxkey, mkq[q]);
        }
    }
    if (mincut == 0xFFFFFFFFu || !isfinite(Z) || Z <= 0.0f) fb = true;

    unsigned Tkeyb = 0;
    int count = 0, bstar = 0, shift = 0;
    const unsigned base = mincut;

    // ---------- fast path: one adaptive histogram over candidate lists ----------
    if (!fb) {
        const unsigned range = maxkey - base;
        while ((range >> shift) > (unsigned)(NB - 1)) shift++;
        for (int i = tid; i <= NB; i += TPB) hist[i] = 0;   // incl hist[2048]
        if (tid == 0) { sh_i1 = -1; scnt = 0; }
        __syncthreads();
        #pragma unroll
        for (int q = 0; q < SPLIT; ++q) {
            const ull* gc = ws_cand + (size_t)(b * SPLIT + q) * LCAND;
            int nl = min((int)cntq[q], LCAND);
            for (int i = tid; i < nl; i += TPB)
                atomicAdd(&hist[((unsigned)(gc[i] >> 32) - base) >> shift], 1u);
        }
        __syncthreads();
        unsigned fat = 0;
        for (int i = tid; i < NB; i += TPB) {
            unsigned h = hist[i];
            cnts[i] = (unsigned short)h;
            fat = max(fat, h);
        }
        #pragma unroll
        for (int d = 32; d > 0; d >>= 1) fat = max(fat, __shfl_down(fat, d));
        if (lane == 0) uscr[w] = fat;
        __syncthreads();
        if (tid == 0) {
            unsigned m2 = 0;
            for (int j = 0; j < 16; ++j) m2 = max(m2, uscr[j]);
            uscr[16] = m2;
        }
        __syncthreads();
        if (uscr[16] > 64u) fb = true;                      // fat bin -> fallback
    }
    if (!fb) {
        suffix_scan_2048(hist, uscr, tid);
        for (int e = tid; e < NB; e += TPB) {
            unsigned Se = hist[e], Sn = (e < NB - 1) ? hist[e + 1] : 0u;
            if (Se >= Ku && Sn < Ku) { sh_i1 = e; sh_u1 = Se; }
        }
        __syncthreads();
        if (sh_i1 < 0) fb = true;
        else {
            bstar = sh_i1;
            count = (int)sh_u1;
            Tkeyb = base + ((unsigned)bstar << shift);
            if (Tkeyb < cutmax || count > CAND2) fb = true; // exactness guards
        }
    }
    if (!fb) {
        #pragma unroll
        for (int q = 0; q < SPLIT; ++q) {
            const ull* gc = ws_cand + (size_t)(b * SPLIT + q) * LCAND;
            int nl = min((int)cntq[q], LCAND);
            for (int i = tid; i < nl; i += TPB) {
                ull e = gc[i];
                unsigned k = (unsigned)(e >> 32);
                if (k >= Tkeyb) {
                    unsigned bin = (k - base) >> shift;
                    unsigned pos = atomicAdd(&hist[bin + 1], 1u);  // base S[bin+1]
                    cand2[pos] = e;
                }
            }
        }
        __syncthreads();
        for (int e = bstar + tid; e < NB; e += TPB) {       // fix multi-elem bins
            int c = (int)cnts[e];
            if (c >= 2) {
                int st = (int)hist[e + 1] - c;
                for (int x = 1; x < c; ++x) {
                    ull key = cand2[st + x];
                    int y = x - 1;
                    while (y >= 0 && cand2[st + y] < key) { cand2[st + y + 1] = cand2[st + y]; --y; }
                    cand2[st + y + 1] = key;
                }
            }
        }
        __syncthreads();
    }

    // ---------- slow path: full-row exact recompute (correctness net) ----------
    if (fb) {
        const float* __restrict__ row = logits + (size_t)b * V;
        float m = -1e30f, z = 0.0f;
        for (int i = tid; i < V; i += TPB) {
            float y = row[i] * invT;
            float nm = fmaxf(m, y);
            z = z * exp2f((m - nm) * L2E) + exp2f((y - nm) * L2E);
            m = nm;
        }
        sh_p[tid] = m; sh_c[tid] = z;
        __syncthreads();
        for (int d = TPB >> 1; d > 0; d >>= 1) {
            if (tid < d) {
                float m1 = sh_p[tid], z1 = sh_c[tid];
                float m2 = sh_p[tid + d], z2 = sh_c[tid + d];
                float mm = fmaxf(m1, m2);
                sh_c[tid] = z1 * exp2f((m1 - mm) * L2E) + z2 * exp2f((m2 - mm) * L2E);
                sh_p[tid] = mm;
            }
            __syncthreads();
        }
        Y = sh_p[0]; Z = sh_c[0];
        __syncthreads();
        for (int i = tid; i < NB; i += TPB) hist[i] = 0;
        if (tid == 0) { sh_i1 = 0; sh_i2 = 0; sh_u1 = 0; }
        __syncthreads();
        for (int i = tid; i < V; i += TPB) atomicAdd(&hist[fkey(row[i]) >> 21], 1u);
        __syncthreads();
        suffix_scan_2048(hist, uscr, tid);
        for (int e = tid; e < NB; e += TPB) {
            unsigned Se = hist[e], Sn = (e < NB-1) ? hist[e+1] : 0u;
            if (Se >= Ku && Sn < Ku) { sh_i1 = e; sh_u1 = Sn; }
        }
        __syncthreads();
        int b1 = sh_i1;
        unsigned cab = sh_u1;
        for (int i = tid; i < NB; i += TPB) hist[i] = 0;
        __syncthreads();
        for (int i = tid; i < V; i += TPB) {
            unsigned k = fkey(row[i]);
            if ((int)(k >> 21) == b1) atomicAdd(&hist[(k >> 10) & (NB - 1)], 1u);
        }
        __syncthreads();
        suffix_scan_2048(hist, uscr, tid);
        for (int e = tid; e < NB; e += TPB) {
            unsigned Se = cab + hist[e];
            unsigned Sn = cab + ((e < NB-1) ? hist[e+1] : 0u);
            if (Se >= Ku && Sn < Ku) sh_i2 = e;
        }
        __syncthreads();
        unsigned Tkey = ((unsigned)b1 << 21) | ((unsigned)sh_i2 << 10);
        if (tid == 0) scnt = 0;
        __syncthreads();
        for (int i = tid; i < V; i += TPB) {
            unsigned k = fkey(row[i]);
            if (k >= Tkey) {
                unsigned pos = atomicAdd(&scnt, 1u);
                if (pos < CAND2) cand[pos] = packkv(k, (unsigned)i);
            }
        }
        __syncthreads();
        count = (scnt < (unsigned)CAND2) ? (int)scnt : CAND2;

        int n_sort = 1;
        while (n_sort < count) n_sort <<= 1;
        for (int i = tid; i < n_sort; i += TPB)
            if (i >= count) cand[i] = 0ull;
        __syncthreads();
        for (int kk = 2; kk <= n_sort; kk <<= 1) {
            for (int j = kk >> 1; j > 0; j >>= 1) {
                for (int i = tid; i < n_sort; i += TPB) {
                    int ixj = i ^ j;
                    if (ixj > i) {
                        ull a = cand[i], c = cand[ixj];
                        bool up = (i & kk) == 0;
                        if (up ? (a < c) : (a > c)) { cand[i] = c; cand[ixj] = a; }
                    }
                }
                __syncthreads();
            }
        }
    }

    ull* srt = fb ? cand : cand2;
    int K = min(Korig, count);

    // ---------- probs for top-K prefix, shuffle prefix-sum ----------
    float pv = 0.0f;
    if (tid < K) {
        unsigned k = (unsigned)(srt[tid] >> 32);
        pv = exp2f((funkey(k) * invT - Y) * L2E) / Z;
    }
    float inc = pv;
    #pragma unroll
    for (int d = 1; d < 64; d <<= 1) { float o = __shfl_up(inc, d); if (lane >= d) inc += o; }
    if (lane == 63) fws[w] = inc;
    __syncthreads();
    if (w == 0) {
        float v = (lane < 16) ? fws[lane] : 0.0f;
        float vi = v;
        #pragma unroll
        for (int d = 1; d < 16; d <<= 1) { float o = __shfl_up(vi, d); if (lane >= d) vi += o; }
        if (lane < 16) fws[16 + lane] = vi - v;
    }
    __syncthreads();
    float cum = inc + fws[16 + w];
    sh_p[tid] = pv;
    sh_c[tid] = cum;
    if (tid == 0) sh_i1 = K;
    __syncthreads();

    // top-p (exclusive cumsum BEFORE masking, as reference)
    if (tid < K) {
        float excl = cum - pv;
        if (excl > top_p) atomicMin(&sh_i1, tid);
    }
    __syncthreads();
    int n1 = sh_i1;
    float thr = sh_p[0] * min_p;
    if (tid == 0) sh_i2 = n1;
    __syncthreads();
    if (tid < n1 && sh_p[tid] < thr) atomicMin(&sh_i2, tid);
    __syncthreads();
    int nf = sh_i2;                         // >= 1
    float total = sh_c[nf - 1];

    // ---------- inverse-CDF sample ----------
    int pred = (tid < nf) && ((sh_c[tid] / total) < uval);
    int rank = __syncthreads_count(pred);
    if (rank > nf - 1) rank = nf - 1;
    if (rank < 0) rank = 0;
    if (tid == 0)
        out_tok[b] = (float)(~(unsigned)(srt[rank] & 0xFFFFFFFFull));

    // ---------- scatter survivors (out_probs zeroed by K1) ----------
    if (tid < nf) {
        unsigned idx = ~(unsigned)(srt[tid] & 0xFFFFFFFFull);
        out_probs[(size_t)b * V + idx] = sh_p[tid] / total;
    }
}

extern "C" void kernel_launch(void* const* d_in, const int* in_sizes, int n_in,
                              void* d_out, int out_size, void* d_ws, size_t ws_size,
                              hipStream_t stream) {
    const float* logits = (const float*)d_in[0];
    const float* temps  = (const float*)d_in[1];
    const int*   top_ks = (const int*)d_in[2];
    const float* top_ps = (const float*)d_in[3];
    const float* min_ps = (const float*)d_in[4];
    const float* u      = (const float*)d_in[5];
    const int B = in_sizes[1];
    const int V = in_sizes[0] / B;
    float* out_tok   = (float*)d_out;
    float* out_probs = out_tok + B;

    int Vq = (((V + SPLIT - 1) / SPLIT) + 3) & ~3;   // chunk, float4-aligned

    char* ws = (char*)d_ws;
    size_t off = 0;
    auto take = [&](size_t bytes) { char* p = ws + off; off = (off + bytes + 255) & ~(size_t)255; return p; };
    float*    ws_cy   = (float*)take((size_t)B * SPLIT * sizeof(float));
    float*    ws_z    = (float*)take((size_t)B * SPLIT * sizeof(float));
    unsigned* ws_cut  = (unsigned*)take((size_t)B * SPLIT * sizeof(unsigned));
    unsigned* ws_cnt  = (unsigned*)take((size_t)B * SPLIT * sizeof(unsigned));
    unsigned* ws_maxk = (unsigned*)take((size_t)B * SPLIT * sizeof(unsigned));
    ull*      ws_cand = (ull*)take((size_t)B * SPLIT * LCAND * sizeof(ull));
    (void)ws_size;

    k0_cut<<<dim3(SPLIT * B), dim3(T0), 0, stream>>>(
        logits, temps, top_ks, ws_cy, ws_cut, V, Vq);
    k1_scan<<<dim3(SPLIT * B), dim3(T1), 0, stream>>>(
        logits, temps, out_probs, ws_cy, ws_cut, ws_z, ws_cnt, ws_maxk, ws_cand, V, Vq);
    k2_sample<<<dim3(B), dim3(TPB), 0, stream>>>(
        logits, temps, top_ks, top_ps, min_ps, u, ws_cy, ws_z, ws_cut, ws_cnt,
        ws_maxk, ws_cand, out_tok, out_probs, V);
}